// Round 2
// baseline (704.111 us; speedup 1.0000x reference)
//
#include <hip/hip_runtime.h>
#include <hip/hip_fp16.h>
#include <math.h>

#define N_NODES 100000
#define N_EDGES 600000
#define NB_SCAN ((N_NODES + 1023) / 1024)   // 98 scan blocks of 1024

typedef unsigned short u16;
typedef __bf16 bf16x8 __attribute__((ext_vector_type(8)));
typedef float  f32x4  __attribute__((ext_vector_type(4)));

__device__ __forceinline__ u16 f2bf(float f) {
    union { float f; unsigned u; } c; c.f = f;
    unsigned u = c.u + 0x7fffu + ((c.u >> 16) & 1u);   // RNE
    return (u16)(u >> 16);
}
__device__ __forceinline__ float bf2f(u16 h) {
    union { unsigned u; float f; } c; c.u = ((unsigned)h) << 16;
    return c.f;
}
// fast tanh: tanh(x) = 1 - 2/(exp(2x)+1); saturates correctly at +-inf.
__device__ __forceinline__ float fast_tanh(float x) {
    float e = __expf(2.0f * x);                 // v_exp_f32 path
    return 1.0f - 2.0f * __builtin_amdgcn_rcpf(e + 1.0f);
}

// ===========================================================================
// CSR build: counting sort of edges by dst (once per launch).
// ===========================================================================
__global__ void hist_k(const int* __restrict__ dst, int* __restrict__ counts,
                       int* __restrict__ rank)
{
    int e = blockIdx.x * 256 + threadIdx.x;
    if (e < N_EDGES) rank[e] = atomicAdd(&counts[dst[e]], 1);
}

__global__ void scan_a_k(const int* __restrict__ counts, int* __restrict__ row_ptr,
                         int* __restrict__ blockSums)
{
    __shared__ int s[256];
    const int t = threadIdx.x;
    const int base = blockIdx.x * 1024 + t * 4;
    int c[4];
#pragma unroll
    for (int j = 0; j < 4; ++j) c[j] = (base + j < N_NODES) ? counts[base + j] : 0;
    const int tot = c[0] + c[1] + c[2] + c[3];
    s[t] = tot;
    __syncthreads();
    for (int off = 1; off < 256; off <<= 1) {
        int v = (t >= off) ? s[t - off] : 0;
        __syncthreads();
        s[t] += v;
        __syncthreads();
    }
    int run = s[t] - tot;
#pragma unroll
    for (int j = 0; j < 4; ++j) {
        if (base + j < N_NODES) row_ptr[base + j] = run;
        run += c[j];
    }
    if (t == 255) blockSums[blockIdx.x] = s[255];
}

__global__ void scan_b_k(const int* __restrict__ blockSums, int* __restrict__ blockOffs)
{
    if (threadIdx.x == 0) {
        int run = 0;
        for (int b = 0; b < NB_SCAN; ++b) { blockOffs[b] = run; run += blockSums[b]; }
    }
}

__global__ void scan_c_k(int* __restrict__ row_ptr, const int* __restrict__ blockOffs)
{
    int i = blockIdx.x * 256 + threadIdx.x;
    if (i < N_NODES) row_ptr[i] += blockOffs[i >> 10];
    if (i == 0) row_ptr[N_NODES] = N_EDGES;
}

__global__ void scatter_k(const int* __restrict__ src, const int* __restrict__ dst,
                          const int* __restrict__ row_ptr, const int* __restrict__ rank,
                          int* __restrict__ perm, int* __restrict__ src_sorted)
{
    int e = blockIdx.x * 256 + threadIdx.x;
    if (e < N_EDGES) {
        int pos = row_ptr[dst[e]] + rank[e];
        perm[pos] = e;
        src_sorted[pos] = src[e];
    }
}

// ===========================================================================
// Weight prep (once per launch): fp32 W[k][n] -> transposed bf16 hi/lo WT[n][k].
// ===========================================================================
__global__ void wprep_k(const float* __restrict__ W1a, const float* __restrict__ W1b,
                        const float* __restrict__ W2a, const float* __restrict__ W2b,
                        const float* __restrict__ Wf1, const float* __restrict__ Wf2,
                        u16* __restrict__ wT)
{
    int idx = blockIdx.x * 256 + threadIdx.x;
    if (idx >= 90112) return;
    int m, local;
    if      (idx < 16384) { m = 0; local = idx; }
    else if (idx < 32768) { m = 1; local = idx - 16384; }
    else if (idx < 49152) { m = 2; local = idx - 32768; }
    else if (idx < 65536) { m = 3; local = idx - 49152; }
    else if (idx < 81920) { m = 4; local = idx - 65536; }
    else                  { m = 5; local = idx - 81920; }
    const int N = (m == 5) ? 64 : 128;
    const float* src = (m == 0) ? W1a : (m == 1) ? W1b : (m == 2) ? W2a
                     : (m == 3) ? W2b : (m == 4) ? Wf1 : Wf2;
    const int k = local / N, n = local % N;
    const float w = src[k * N + n];
    const u16 hi = f2bf(w);
    const u16 lo = f2bf(w - bf2f(hi));
    const int base = m * 32768;
    const int sz   = (m == 5) ? 8192 : 16384;
    wT[base + n * 128 + k]      = hi;
    wT[base + sz + n * 128 + k] = lo;
}

// ===========================================================================
// FUSED edge-linear + gather + relu + CSR aggregation (round 8).
//   agg[n] = sum_{e: dst=n} relu( x[src_e] + ef[e]@We + be )
// One node per wave (edge list wave-uniform). Each lane owns 2 channels;
// its We column-pair lives in 64 VGPRs. Per 8-edge batch:
//   - 1 float4/lane cooperative ef load (8 lanes per edge) -> LDS
//   - 8 float2 x-row gathers into regs (prefetched one batch ahead)
//   - ef broadcast back via same-address ds_read_b128 (conflict-free)
//   - 64 FMA/edge/lane; relu+acc predicated on edge validity.
// Eliminates the e_s materialization (153.6 MB write + 153.6 MB read) and
// the separate edge_lin GEMM dispatches entirely.
// ===========================================================================
__global__ __launch_bounds__(256, 4) void fused_agg_k(
    const float* __restrict__ x, const float* __restrict__ ef,
    const int* __restrict__ perm, const int* __restrict__ src_s,
    const int* __restrict__ row_ptr,
    const float* __restrict__ We, const float* __restrict__ be,
    float* __restrict__ agg)
{
    __shared__ float sEf[4][8][32];          // per-wave 8-edge ef batch (4 KB)
    const int tid  = threadIdx.x;
    const int lane = tid & 63;
    const int wave = tid >> 6;
    const int node = blockIdx.x * 4 + wave;
    if (node >= N_NODES) return;             // wave-uniform

    const int c2 = lane * 2;

    const int start = row_ptr[node];
    const int end   = row_ptr[node + 1];

    if (start == end) {                      // isolated node: agg = 0
        *(float2*)(agg + (size_t)node * 128 + c2) = make_float2(0.f, 0.f);
        return;
    }

    // per-lane weight columns: w[k] = (We[k][c2], We[k][c2+1])  (64 VGPR)
    float2 w[32];
#pragma unroll
    for (int k = 0; k < 32; ++k)
        w[k] = *(const float2*)(We + k * 128 + c2);
    const float2 bev = *(const float2*)(be + c2);

    const int slot = lane >> 3;              // edge slot this lane stages
    const int q    = lane & 7;               // float4 quarter within 32 floats
    const int last = end - 1;

    // ---- prefetch batch 0 ----
    float4 efreg;
    {
        const int ii = start + slot;
        const int e  = perm[ii < end ? ii : last];
        efreg = *(const float4*)(ef + (size_t)e * 32 + q * 4);
    }
    float2 xv[8];
#pragma unroll
    for (int b = 0; b < 8; ++b) {
        const int ii = start + b;
        const int s  = src_s[ii < end ? ii : last];
        xv[b] = *(const float2*)(x + (size_t)s * 128 + c2);
    }

    float acc0 = 0.f, acc1 = 0.f;

    for (int i = start; i < end; i += 8) {
        // stage current ef batch to this wave's LDS slab
        *(float4*)&sEf[wave][slot][q * 4] = efreg;

        // ---- prefetch next batch (wave-uniform guard) ----
        const int inext = i + 8;
        float4 efn = efreg;
        float2 xn[8];
#pragma unroll
        for (int b = 0; b < 8; ++b) xn[b] = xv[b];
        if (inext < end) {
            const int ii = inext + slot;
            const int e  = perm[ii < end ? ii : last];
            efn = *(const float4*)(ef + (size_t)e * 32 + q * 4);
#pragma unroll
            for (int b = 0; b < 8; ++b) {
                const int jj = inext + b;
                const int s  = src_s[jj < end ? jj : last];
                xn[b] = *(const float2*)(x + (size_t)s * 128 + c2);
            }
        }

        // ---- compute 8 edges (ds_read same-address broadcast) ----
#pragma unroll
        for (int b = 0; b < 8; ++b) {
            float e0 = bev.x, e1 = bev.y;
#pragma unroll
            for (int k4 = 0; k4 < 8; ++k4) {
                const float4 f = *(const float4*)&sEf[wave][b][k4 * 4];
                e0 = fmaf(f.x, w[k4 * 4 + 0].x, e0); e1 = fmaf(f.x, w[k4 * 4 + 0].y, e1);
                e0 = fmaf(f.y, w[k4 * 4 + 1].x, e0); e1 = fmaf(f.y, w[k4 * 4 + 1].y, e1);
                e0 = fmaf(f.z, w[k4 * 4 + 2].x, e0); e1 = fmaf(f.z, w[k4 * 4 + 2].y, e1);
                e0 = fmaf(f.w, w[k4 * 4 + 3].x, e0); e1 = fmaf(f.w, w[k4 * 4 + 3].y, e1);
            }
            const float v0 = fmaxf(xv[b].x + e0, 0.f);
            const float v1 = fmaxf(xv[b].y + e1, 0.f);
            if (i + b < end) { acc0 += v0; acc1 += v1; }
        }

        efreg = efn;
#pragma unroll
        for (int b = 0; b < 8; ++b) xv[b] = xn[b];
    }

    *(float2*)(agg + (size_t)node * 128 + c2) = make_float2(acc0, acc1);
}

// ===========================================================================
// Fused 2-layer node MLP via bf16 hi/lo split MFMA (16x16x32) — unchanged
// from round 7 (column-split wave mapping, B-frags reused across 4 row
// subtiles, acc held across barrier, fast_tanh).
// ===========================================================================
template <int NT2, bool TANH1, bool TANHF, bool ADDAGG>
__global__ __launch_bounds__(256, 4) void mlp2_mfma_k(
    const float* __restrict__ xin, const float* __restrict__ agg,
    const u16* __restrict__ WaT_hi, const u16* __restrict__ WaT_lo,
    const float* __restrict__ ba,
    const u16* __restrict__ WbT_hi, const u16* __restrict__ WbT_lo,
    const float* __restrict__ bb,
    float* __restrict__ out)
{
    __shared__ u16 sHi[64][136];
    __shared__ u16 sLo[64][136];
    const int tid = threadIdx.x;
    const int n0  = blockIdx.x * 64;

    // ---- stage tile: fp32 (xin + agg) -> bf16 hi/lo in LDS ----
    {
        const int mrow = tid >> 5, kq = tid & 31;
#pragma unroll
        for (int g = 0; g < 8; ++g) {
            const int row  = g * 8 + mrow;
            const int node = n0 + row;
            float4 v = make_float4(0.f, 0.f, 0.f, 0.f);
            if (node < N_NODES) {
                v = *(const float4*)(xin + (size_t)node * 128 + kq * 4);
                if (ADDAGG) {
                    float4 a4 = *(const float4*)(agg + (size_t)node * 128 + kq * 4);
                    v.x += a4.x; v.y += a4.y; v.z += a4.z; v.w += a4.w;
                }
            }
            const u16 h0 = f2bf(v.x), h1 = f2bf(v.y), h2 = f2bf(v.z), h3 = f2bf(v.w);
            const u16 l0 = f2bf(v.x - bf2f(h0)), l1 = f2bf(v.y - bf2f(h1));
            const u16 l2 = f2bf(v.z - bf2f(h2)), l3 = f2bf(v.w - bf2f(h3));
            *(uint2*)&sHi[row][kq * 4] =
                make_uint2((unsigned)h0 | ((unsigned)h1 << 16), (unsigned)h2 | ((unsigned)h3 << 16));
            *(uint2*)&sLo[row][kq * 4] =
                make_uint2((unsigned)l0 | ((unsigned)l1 << 16), (unsigned)l2 | ((unsigned)l3 << 16));
        }
    }
    __syncthreads();

    const int lane = tid & 63, wave = tid >> 6;
    const int quad = lane >> 4, col = lane & 15;

    // ---- layer A: wave w owns col-tiles nt = 2w+j (j=0,1), all 64 rows ----
    f32x4 accA[2][4];
#pragma unroll
    for (int j = 0; j < 2; ++j) {
        const int nt = wave * 2 + j;
        const float bv = ba[nt * 16 + col];
#pragma unroll
        for (int m = 0; m < 4; ++m) accA[j][m] = (f32x4){bv, bv, bv, bv};

        bf16x8 bHi[4], bLo[4];
#pragma unroll
        for (int k0 = 0; k0 < 4; ++k0) {
            const size_t off = (size_t)(nt * 16 + col) * 128 + k0 * 32 + quad * 8;
            bHi[k0] = *(const bf16x8*)(WaT_hi + off);
            bLo[k0] = *(const bf16x8*)(WaT_lo + off);
        }
#pragma unroll 2
        for (int m = 0; m < 4; ++m) {
#pragma unroll
            for (int k0 = 0; k0 < 4; ++k0) {
                const bf16x8 aHi = *(const bf16x8*)&sHi[m * 16 + col][k0 * 32 + quad * 8];
                const bf16x8 aLo = *(const bf16x8*)&sLo[m * 16 + col][k0 * 32 + quad * 8];
                accA[j][m] = __builtin_amdgcn_mfma_f32_16x16x32_bf16(aHi, bHi[k0], accA[j][m], 0, 0, 0);
                accA[j][m] = __builtin_amdgcn_mfma_f32_16x16x32_bf16(aHi, bLo[k0], accA[j][m], 0, 0, 0);
                accA[j][m] = __builtin_amdgcn_mfma_f32_16x16x32_bf16(aLo, bHi[k0], accA[j][m], 0, 0, 0);
            }
        }
    }
    __syncthreads();   // all waves done READING the input tile

    // ---- act1 + hi/lo re-split of t into the same LDS buffer ----
#pragma unroll
    for (int j = 0; j < 2; ++j) {
        const int ct = (wave * 2 + j) * 16 + col;
#pragma unroll
        for (int m = 0; m < 4; ++m) {
#pragma unroll
            for (int r = 0; r < 4; ++r) {
                float v = TANH1 ? fast_tanh(accA[j][m][r]) : fmaxf(accA[j][m][r], 0.f);
                const u16 hv = f2bf(v);
                const u16 lv = f2bf(v - bf2f(hv));
                const int row = m * 16 + quad * 4 + r;
                sHi[row][ct] = hv;
                sLo[row][ct] = lv;
            }
        }
    }
    __syncthreads();   // t tile fully written

    // ---- layer B: same mapping; head (NT2=4) = 1 col-tile per wave ----
    constexpr int JB   = NT2 / 4;
    constexpr int NOUT = NT2 * 16;
#pragma unroll
    for (int j = 0; j < JB; ++j) {
        const int nt = wave * JB + j;
        const float bv = bb[nt * 16 + col];
        f32x4 accB[4];
#pragma unroll
        for (int m = 0; m < 4; ++m) accB[m] = (f32x4){bv, bv, bv, bv};

        bf16x8 bHi[4], bLo[4];
#pragma unroll
        for (int k0 = 0; k0 < 4; ++k0) {
            const size_t off = (size_t)(nt * 16 + col) * 128 + k0 * 32 + quad * 8;
            bHi[k0] = *(const bf16x8*)(WbT_hi + off);
            bLo[k0] = *(const bf16x8*)(WbT_lo + off);
        }
#pragma unroll 2
        for (int m = 0; m < 4; ++m) {
#pragma unroll
            for (int k0 = 0; k0 < 4; ++k0) {
                const bf16x8 tHi = *(const bf16x8*)&sHi[m * 16 + col][k0 * 32 + quad * 8];
                const bf16x8 tLo = *(const bf16x8*)&sLo[m * 16 + col][k0 * 32 + quad * 8];
                accB[m] = __builtin_amdgcn_mfma_f32_16x16x32_bf16(tHi, bHi[k0], accB[m], 0, 0, 0);
                accB[m] = __builtin_amdgcn_mfma_f32_16x16x32_bf16(tHi, bLo[k0], accB[m], 0, 0, 0);
                accB[m] = __builtin_amdgcn_mfma_f32_16x16x32_bf16(tLo, bHi[k0], accB[m], 0, 0, 0);
            }
        }
#pragma unroll
        for (int m = 0; m < 4; ++m) {
#pragma unroll
            for (int r = 0; r < 4; ++r) {
                const int node = n0 + m * 16 + quad * 4 + r;
                if (node < N_NODES) {
                    float v = accB[m][r];
                    if (TANHF) v = fast_tanh(v);
                    out[(size_t)node * NOUT + nt * 16 + col] = v;
                }
            }
        }
    }
}

// ---------------------------------------------------------------------------
extern "C" void kernel_launch(void* const* d_in, const int* in_sizes, int n_in,
                              void* d_out, int out_size, void* d_ws, size_t ws_size,
                              hipStream_t stream)
{
    const float* x   = (const float*)d_in[0];
    const int*   ei  = (const int*)  d_in[1];
    const float* ef  = (const float*)d_in[2];
    const float* We1 = (const float*)d_in[3];
    const float* be1 = (const float*)d_in[4];
    const float* W1a = (const float*)d_in[5];
    const float* b1a = (const float*)d_in[6];
    const float* W1b = (const float*)d_in[7];
    const float* b1b = (const float*)d_in[8];
    const float* We2 = (const float*)d_in[9];
    const float* be2 = (const float*)d_in[10];
    const float* W2a = (const float*)d_in[11];
    const float* b2a = (const float*)d_in[12];
    const float* W2b = (const float*)d_in[13];
    const float* b2b = (const float*)d_in[14];
    const float* Wf1 = (const float*)d_in[15];
    const float* bf1 = (const float*)d_in[16];
    const float* Wf2 = (const float*)d_in[17];
    const float* bf2 = (const float*)d_in[18];
    float* out = (float*)d_out;

    const int* src = ei;             // edge_index[0]
    const int* dst = ei + N_EDGES;   // edge_index[1]

    // ---- workspace layout (unchanged offsets; e_s slab now unused) ----
    float*  agg     = (float*)d_ws;                      // N*128 f
    float*  h       = agg + (size_t)N_NODES * 128;       // N*128 f
    int*    row_ptr = (int*)(h + (size_t)N_NODES * 128); // N+8 (padded)
    int*    perm    = row_ptr + (N_NODES + 8);           // E
    int*    src_s   = perm + N_EDGES;                    // E
    __half* e_s     = (__half*)(src_s + N_EDGES);        // (dead slab)
    u16*    wT      = (u16*)(e_s + (size_t)N_EDGES * 128); // 180224 u16 bf16 weights
    // sort temporaries overlaid on agg (dead before fused_agg_k writes agg):
    int* counts    = (int*)agg;                          // N
    int* rank      = counts + N_NODES;                   // E
    int* blockSums = rank + N_EDGES;                     // NB_SCAN
    int* blockOffs = blockSums + NB_SCAN;                // NB_SCAN

    // transposed bf16 weight blocks (hi at +0, lo at +size)
    u16* W1aT = wT;                  // 16384 hi + 16384 lo
    u16* W1bT = wT + 32768;
    u16* W2aT = wT + 65536;
    u16* W2bT = wT + 98304;
    u16* Wf1T = wT + 131072;
    u16* Wf2T = wT + 163840;         // 8192 hi + 8192 lo

    const int mlpGrid = (N_NODES + 63) / 64;
    const int fGrid   = (N_NODES + 3) / 4;      // fused agg: 1 node per wave
    const int eGrid   = (N_EDGES + 255) / 256;
    const int nGrid   = (N_NODES + 255) / 256;
    const int wpGrid  = (90112 + 255) / 256;

    // ---- build sorted CSR + bf16 weights (same work every call) ----
    hipMemsetAsync(counts, 0, (size_t)N_NODES * sizeof(int), stream);
    hist_k   <<<eGrid,   256, 0, stream>>>(dst, counts, rank);
    wprep_k  <<<wpGrid,  256, 0, stream>>>(W1a, W1b, W2a, W2b, Wf1, Wf2, wT);
    scan_a_k <<<NB_SCAN, 256, 0, stream>>>(counts, row_ptr, blockSums);
    scan_b_k <<<1,        64, 0, stream>>>(blockSums, blockOffs);
    scan_c_k <<<nGrid,   256, 0, stream>>>(row_ptr, blockOffs);
    scatter_k<<<eGrid,   256, 0, stream>>>(src, dst, row_ptr, rank, perm, src_s);

    // ---- conv1 (fused edge-linear + aggregation) ----
    fused_agg_k<<<fGrid, 256, 0, stream>>>(x, ef, perm, src_s, row_ptr, We1, be1, agg);
    mlp2_mfma_k<8, false, true, true><<<mlpGrid, 256, 0, stream>>>(
        x, agg, W1aT, W1aT + 16384, b1a, W1bT, W1bT + 16384, b1b, h);

    // ---- conv2 ----
    fused_agg_k<<<fGrid, 256, 0, stream>>>(h, ef, perm, src_s, row_ptr, We2, be2, agg);
    mlp2_mfma_k<8, false, true, true><<<mlpGrid, 256, 0, stream>>>(
        h, agg, W2aT, W2aT + 16384, b2a, W2bT, W2bT + 16384, b2b, h);

    // ---- head ----
    mlp2_mfma_k<4, true, false, false><<<mlpGrid, 256, 0, stream>>>(
        h, nullptr, Wf1T, Wf1T + 16384, bf1, Wf2T, Wf2T + 8192, bf2, out);
}

// Round 3
// 573.794 us; speedup vs baseline: 1.2271x; 1.2271x over previous
//
#include <hip/hip_runtime.h>
#include <hip/hip_fp16.h>
#include <math.h>

#define N_NODES 100000
#define N_EDGES 600000
#define NB_SCAN ((N_NODES + 1023) / 1024)   // 98 scan blocks of 1024

typedef unsigned short u16;
typedef __bf16 bf16x8 __attribute__((ext_vector_type(8)));
typedef float  f32x4  __attribute__((ext_vector_type(4)));

__device__ __forceinline__ u16 f2bf(float f) {
    union { float f; unsigned u; } c; c.f = f;
    unsigned u = c.u + 0x7fffu + ((c.u >> 16) & 1u);   // RNE
    return (u16)(u >> 16);
}
__device__ __forceinline__ float bf2f(u16 h) {
    union { unsigned u; float f; } c; c.u = ((unsigned)h) << 16;
    return c.f;
}
// fast tanh: tanh(x) = 1 - 2/(exp(2x)+1); saturates correctly at +-inf.
__device__ __forceinline__ float fast_tanh(float x) {
    float e = __expf(2.0f * x);                 // v_exp_f32 path
    return 1.0f - 2.0f * __builtin_amdgcn_rcpf(e + 1.0f);
}

// ===========================================================================
// CSR build: counting sort of edges by dst (once per launch).
// ===========================================================================
__global__ void hist_k(const int* __restrict__ dst, int* __restrict__ counts,
                       int* __restrict__ rank)
{
    int e = blockIdx.x * 256 + threadIdx.x;
    if (e < N_EDGES) rank[e] = atomicAdd(&counts[dst[e]], 1);
}

__global__ void scan_a_k(const int* __restrict__ counts, int* __restrict__ row_ptr,
                         int* __restrict__ blockSums)
{
    __shared__ int s[256];
    const int t = threadIdx.x;
    const int base = blockIdx.x * 1024 + t * 4;
    int c[4];
#pragma unroll
    for (int j = 0; j < 4; ++j) c[j] = (base + j < N_NODES) ? counts[base + j] : 0;
    const int tot = c[0] + c[1] + c[2] + c[3];
    s[t] = tot;
    __syncthreads();
    for (int off = 1; off < 256; off <<= 1) {
        int v = (t >= off) ? s[t - off] : 0;
        __syncthreads();
        s[t] += v;
        __syncthreads();
    }
    int run = s[t] - tot;
#pragma unroll
    for (int j = 0; j < 4; ++j) {
        if (base + j < N_NODES) row_ptr[base + j] = run;
        run += c[j];
    }
    if (t == 255) blockSums[blockIdx.x] = s[255];
}

__global__ void scan_b_k(const int* __restrict__ blockSums, int* __restrict__ blockOffs)
{
    if (threadIdx.x == 0) {
        int run = 0;
        for (int b = 0; b < NB_SCAN; ++b) { blockOffs[b] = run; run += blockSums[b]; }
    }
}

__global__ void scan_c_k(int* __restrict__ row_ptr, const int* __restrict__ blockOffs)
{
    int i = blockIdx.x * 256 + threadIdx.x;
    if (i < N_NODES) row_ptr[i] += blockOffs[i >> 10];
    if (i == 0) row_ptr[N_NODES] = N_EDGES;
}

__global__ void scatter_k(const int* __restrict__ src, const int* __restrict__ dst,
                          const int* __restrict__ row_ptr, const int* __restrict__ rank,
                          int* __restrict__ perm, int* __restrict__ src_sorted,
                          int* __restrict__ dst_sorted)
{
    int e = blockIdx.x * 256 + threadIdx.x;
    if (e < N_EDGES) {
        int pos = row_ptr[dst[e]] + rank[e];
        perm[pos] = e;
        src_sorted[pos] = src[e];
        dst_sorted[pos] = dst[e];
    }
}

// ===========================================================================
// Weight prep (once per launch): fp32 W[k][n] -> transposed bf16 hi/lo WT[n][k].
// ===========================================================================
__global__ void wprep_k(const float* __restrict__ W1a, const float* __restrict__ W1b,
                        const float* __restrict__ W2a, const float* __restrict__ W2b,
                        const float* __restrict__ Wf1, const float* __restrict__ Wf2,
                        u16* __restrict__ wT)
{
    int idx = blockIdx.x * 256 + threadIdx.x;
    if (idx >= 90112) return;
    int m, local;
    if      (idx < 16384) { m = 0; local = idx; }
    else if (idx < 32768) { m = 1; local = idx - 16384; }
    else if (idx < 49152) { m = 2; local = idx - 32768; }
    else if (idx < 65536) { m = 3; local = idx - 49152; }
    else if (idx < 81920) { m = 4; local = idx - 65536; }
    else                  { m = 5; local = idx - 81920; }
    const int N = (m == 5) ? 64 : 128;
    const float* src = (m == 0) ? W1a : (m == 1) ? W1b : (m == 2) ? W2a
                     : (m == 3) ? W2b : (m == 4) ? Wf1 : Wf2;
    const int k = local / N, n = local % N;
    const float w = src[k * N + n];
    const u16 hi = f2bf(w);
    const u16 lo = f2bf(w - bf2f(hi));
    const int base = m * 32768;
    const int sz   = (m == 5) ? 8192 : 16384;
    wT[base + n * 128 + k]      = hi;
    wT[base + sz + n * 128 + k] = lo;
}

// ===========================================================================
// FUSED conv kernel (round 9): edge-linear GEMM + x-gather + relu + CSR
// segment-sum, one block per 64 sorted edges.
//   Phase 1 (= proven edge_lin_gemm structure): stage We (16KB) + ef rows in
//     LDS, compute e = ef@We + be into regs; gather x[src] float4/thread,
//     add + relu -> msg[64][132] fp32 in LDS (overlays the GEMM buffers).
//   Phase 2: edges are dst-sorted, so the block spans ~12 consecutive nodes.
//     Wave w segment-sums msg rows for nodes nF+w, nF+w+4, ... (lane = 2
//     channels). Nodes fully inside the block: plain float2 store to agg.
//     Boundary nodes (~2/block): atomicAdd (agg pre-zeroed by memset).
// Eliminates e_s materialization AND the separate gather/agg pass.
// ===========================================================================
__global__ __launch_bounds__(256) void fused_conv_k(
    const float* __restrict__ x, const float* __restrict__ ef,
    const int* __restrict__ perm, const int* __restrict__ src_s,
    const int* __restrict__ dst_s, const int* __restrict__ row_ptr,
    const float* __restrict__ We, const float* __restrict__ be,
    float* __restrict__ agg)
{
    __shared__ __align__(16) char smem[33792];      // union: phase1 | msg
    float (*sWe)[128] = (float (*)[128])smem;                // 16384 B
    float (*sEf)[36]  = (float (*)[36])(smem + 16384);       //  9216 B
    float (*msg)[132] = (float (*)[132])smem;                // 33792 B
    __shared__ int sSrc[64];
    __shared__ int sDst[64];

    const int t  = threadIdx.x;
    const int i0 = blockIdx.x * 64;

    // ---- stage We, edge ids, ef rows ----
    {
        const float4* W4 = (const float4*)We;
        float4* S4 = (float4*)(&sWe[0][0]);
#pragma unroll
        for (int j = 0; j < 4; ++j) S4[t + j * 256] = W4[t + j * 256];
    }
    if (t < 64) { sSrc[t] = src_s[i0 + t]; sDst[t] = dst_s[i0 + t]; }
    {
        const int row = t >> 2;
        const int q   = t & 3;
        const int e   = perm[i0 + row];
        const float4* p = (const float4*)(ef + (size_t)e * 32);
        const float4 v0 = p[q];
        const float4 v1 = p[q + 4];
        *(float4*)(&sEf[row][q * 4])       = v0;
        *(float4*)(&sEf[row][(q + 4) * 4]) = v1;
    }
    __syncthreads();

    // ---- phase 1: e = ef @ We + be for 8 edges x 4 channels per thread ----
    const int c  = (t & 31) * 4;
    const int s0 = (t >> 5) * 8;
    float4 acc[8];
    const float4 bv = *(const float4*)(be + c);
#pragma unroll
    for (int s = 0; s < 8; ++s) acc[s] = bv;

#pragma unroll 8
    for (int k = 0; k < 32; ++k) {
        const float4 w = *(const float4*)(&sWe[k][c]);
#pragma unroll
        for (int s = 0; s < 8; ++s) {
            const float a = sEf[s0 + s][k];
            acc[s].x = fmaf(a, w.x, acc[s].x);
            acc[s].y = fmaf(a, w.y, acc[s].y);
            acc[s].z = fmaf(a, w.z, acc[s].z);
            acc[s].w = fmaf(a, w.w, acc[s].w);
        }
    }

    // ---- x gather + add + relu (registers; LDS still holds GEMM bufs) ----
#pragma unroll
    for (int s = 0; s < 8; ++s) {
        const float4 xv = *(const float4*)(x + (size_t)sSrc[s0 + s] * 128 + c);
        acc[s].x = fmaxf(acc[s].x + xv.x, 0.f);
        acc[s].y = fmaxf(acc[s].y + xv.y, 0.f);
        acc[s].z = fmaxf(acc[s].z + xv.z, 0.f);
        acc[s].w = fmaxf(acc[s].w + xv.w, 0.f);
    }
    __syncthreads();            // GEMM LDS reads complete -> safe to overlay
#pragma unroll
    for (int s = 0; s < 8; ++s) *(float4*)(&msg[s0 + s][c]) = acc[s];
    __syncthreads();

    // ---- phase 2: per-node segment sum + store/atomic ----
    const int lane = t & 63, wave = t >> 6;
    const int c2 = lane * 2;
    const int nF = sDst[0], nL = sDst[63];
    for (int n = nF + wave; n <= nL; n += 4) {
        const int rs = row_ptr[n];
        const int re = row_ptr[n + 1];
        const int lo = rs > i0 ? rs : i0;
        const int hi = re < i0 + 64 ? re : i0 + 64;
        float a0 = 0.f, a1 = 0.f;
        for (int i = lo; i < hi; ++i) {
            const float2 v = *(const float2*)(&msg[i - i0][c2]);
            a0 += v.x; a1 += v.y;
        }
        float* dp = agg + (size_t)n * 128 + c2;
        const bool interior = (rs >= i0) && (re <= i0 + 64);
        if (interior) {
            *(float2*)dp = make_float2(a0, a1);
        } else if (hi > lo) {
            atomicAdd(dp,     a0);
            atomicAdd(dp + 1, a1);
        }
    }
}

// ===========================================================================
// Fused 2-layer node MLP via bf16 hi/lo split MFMA (16x16x32) — unchanged
// from round 7 (column-split wave mapping, B-frags reused across 4 row
// subtiles, acc held across barrier, fast_tanh).
// ===========================================================================
template <int NT2, bool TANH1, bool TANHF, bool ADDAGG>
__global__ __launch_bounds__(256, 4) void mlp2_mfma_k(
    const float* __restrict__ xin, const float* __restrict__ agg,
    const u16* __restrict__ WaT_hi, const u16* __restrict__ WaT_lo,
    const float* __restrict__ ba,
    const u16* __restrict__ WbT_hi, const u16* __restrict__ WbT_lo,
    const float* __restrict__ bb,
    float* __restrict__ out)
{
    __shared__ u16 sHi[64][136];
    __shared__ u16 sLo[64][136];
    const int tid = threadIdx.x;
    const int n0  = blockIdx.x * 64;

    // ---- stage tile: fp32 (xin + agg) -> bf16 hi/lo in LDS ----
    {
        const int mrow = tid >> 5, kq = tid & 31;
#pragma unroll
        for (int g = 0; g < 8; ++g) {
            const int row  = g * 8 + mrow;
            const int node = n0 + row;
            float4 v = make_float4(0.f, 0.f, 0.f, 0.f);
            if (node < N_NODES) {
                v = *(const float4*)(xin + (size_t)node * 128 + kq * 4);
                if (ADDAGG) {
                    float4 a4 = *(const float4*)(agg + (size_t)node * 128 + kq * 4);
                    v.x += a4.x; v.y += a4.y; v.z += a4.z; v.w += a4.w;
                }
            }
            const u16 h0 = f2bf(v.x), h1 = f2bf(v.y), h2 = f2bf(v.z), h3 = f2bf(v.w);
            const u16 l0 = f2bf(v.x - bf2f(h0)), l1 = f2bf(v.y - bf2f(h1));
            const u16 l2 = f2bf(v.z - bf2f(h2)), l3 = f2bf(v.w - bf2f(h3));
            *(uint2*)&sHi[row][kq * 4] =
                make_uint2((unsigned)h0 | ((unsigned)h1 << 16), (unsigned)h2 | ((unsigned)h3 << 16));
            *(uint2*)&sLo[row][kq * 4] =
                make_uint2((unsigned)l0 | ((unsigned)l1 << 16), (unsigned)l2 | ((unsigned)l3 << 16));
        }
    }
    __syncthreads();

    const int lane = tid & 63, wave = tid >> 6;
    const int quad = lane >> 4, col = lane & 15;

    // ---- layer A: wave w owns col-tiles nt = 2w+j (j=0,1), all 64 rows ----
    f32x4 accA[2][4];
#pragma unroll
    for (int j = 0; j < 2; ++j) {
        const int nt = wave * 2 + j;
        const float bv = ba[nt * 16 + col];
#pragma unroll
        for (int m = 0; m < 4; ++m) accA[j][m] = (f32x4){bv, bv, bv, bv};

        bf16x8 bHi[4], bLo[4];
#pragma unroll
        for (int k0 = 0; k0 < 4; ++k0) {
            const size_t off = (size_t)(nt * 16 + col) * 128 + k0 * 32 + quad * 8;
            bHi[k0] = *(const bf16x8*)(WaT_hi + off);
            bLo[k0] = *(const bf16x8*)(WaT_lo + off);
        }
#pragma unroll 2
        for (int m = 0; m < 4; ++m) {
#pragma unroll
            for (int k0 = 0; k0 < 4; ++k0) {
                const bf16x8 aHi = *(const bf16x8*)&sHi[m * 16 + col][k0 * 32 + quad * 8];
                const bf16x8 aLo = *(const bf16x8*)&sLo[m * 16 + col][k0 * 32 + quad * 8];
                accA[j][m] = __builtin_amdgcn_mfma_f32_16x16x32_bf16(aHi, bHi[k0], accA[j][m], 0, 0, 0);
                accA[j][m] = __builtin_amdgcn_mfma_f32_16x16x32_bf16(aHi, bLo[k0], accA[j][m], 0, 0, 0);
                accA[j][m] = __builtin_amdgcn_mfma_f32_16x16x32_bf16(aLo, bHi[k0], accA[j][m], 0, 0, 0);
            }
        }
    }
    __syncthreads();   // all waves done READING the input tile

    // ---- act1 + hi/lo re-split of t into the same LDS buffer ----
#pragma unroll
    for (int j = 0; j < 2; ++j) {
        const int ct = (wave * 2 + j) * 16 + col;
#pragma unroll
        for (int m = 0; m < 4; ++m) {
#pragma unroll
            for (int r = 0; r < 4; ++r) {
                float v = TANH1 ? fast_tanh(accA[j][m][r]) : fmaxf(accA[j][m][r], 0.f);
                const u16 hv = f2bf(v);
                const u16 lv = f2bf(v - bf2f(hv));
                const int row = m * 16 + quad * 4 + r;
                sHi[row][ct] = hv;
                sLo[row][ct] = lv;
            }
        }
    }
    __syncthreads();   // t tile fully written

    // ---- layer B: same mapping; head (NT2=4) = 1 col-tile per wave ----
    constexpr int JB   = NT2 / 4;
    constexpr int NOUT = NT2 * 16;
#pragma unroll
    for (int j = 0; j < JB; ++j) {
        const int nt = wave * JB + j;
        const float bv = bb[nt * 16 + col];
        f32x4 accB[4];
#pragma unroll
        for (int m = 0; m < 4; ++m) accB[m] = (f32x4){bv, bv, bv, bv};

        bf16x8 bHi[4], bLo[4];
#pragma unroll
        for (int k0 = 0; k0 < 4; ++k0) {
            const size_t off = (size_t)(nt * 16 + col) * 128 + k0 * 32 + quad * 8;
            bHi[k0] = *(const bf16x8*)(WbT_hi + off);
            bLo[k0] = *(const bf16x8*)(WbT_lo + off);
        }
#pragma unroll 2
        for (int m = 0; m < 4; ++m) {
#pragma unroll
            for (int k0 = 0; k0 < 4; ++k0) {
                const bf16x8 tHi = *(const bf16x8*)&sHi[m * 16 + col][k0 * 32 + quad * 8];
                const bf16x8 tLo = *(const bf16x8*)&sLo[m * 16 + col][k0 * 32 + quad * 8];
                accB[m] = __builtin_amdgcn_mfma_f32_16x16x32_bf16(tHi, bHi[k0], accB[m], 0, 0, 0);
                accB[m] = __builtin_amdgcn_mfma_f32_16x16x32_bf16(tHi, bLo[k0], accB[m], 0, 0, 0);
                accB[m] = __builtin_amdgcn_mfma_f32_16x16x32_bf16(tLo, bHi[k0], accB[m], 0, 0, 0);
            }
        }
#pragma unroll
        for (int m = 0; m < 4; ++m) {
#pragma unroll
            for (int r = 0; r < 4; ++r) {
                const int node = n0 + m * 16 + quad * 4 + r;
                if (node < N_NODES) {
                    float v = accB[m][r];
                    if (TANHF) v = fast_tanh(v);
                    out[(size_t)node * NOUT + nt * 16 + col] = v;
                }
            }
        }
    }
}

// ---------------------------------------------------------------------------
extern "C" void kernel_launch(void* const* d_in, const int* in_sizes, int n_in,
                              void* d_out, int out_size, void* d_ws, size_t ws_size,
                              hipStream_t stream)
{
    const float* x   = (const float*)d_in[0];
    const int*   ei  = (const int*)  d_in[1];
    const float* ef  = (const float*)d_in[2];
    const float* We1 = (const float*)d_in[3];
    const float* be1 = (const float*)d_in[4];
    const float* W1a = (const float*)d_in[5];
    const float* b1a = (const float*)d_in[6];
    const float* W1b = (const float*)d_in[7];
    const float* b1b = (const float*)d_in[8];
    const float* We2 = (const float*)d_in[9];
    const float* be2 = (const float*)d_in[10];
    const float* W2a = (const float*)d_in[11];
    const float* b2a = (const float*)d_in[12];
    const float* W2b = (const float*)d_in[13];
    const float* b2b = (const float*)d_in[14];
    const float* Wf1 = (const float*)d_in[15];
    const float* bf1 = (const float*)d_in[16];
    const float* Wf2 = (const float*)d_in[17];
    const float* bf2 = (const float*)d_in[18];
    float* out = (float*)d_out;

    const int* src = ei;             // edge_index[0]
    const int* dst = ei + N_EDGES;   // edge_index[1]

    // ---- workspace layout ----
    float*  agg     = (float*)d_ws;                      // N*128 f
    float*  h       = agg + (size_t)N_NODES * 128;       // N*128 f
    int*    row_ptr = (int*)(h + (size_t)N_NODES * 128); // N+8 (padded)
    int*    perm    = row_ptr + (N_NODES + 8);           // E
    int*    src_s   = perm + N_EDGES;                    // E
    int*    dst_srt = src_s + N_EDGES;                   // E (new)
    u16*    wT      = (u16*)(dst_srt + N_EDGES);         // 180224 u16 bf16 weights
    // sort temporaries overlaid on agg (dead before agg memset):
    int* counts    = (int*)agg;                          // N
    int* rank      = counts + N_NODES;                   // E
    int* blockSums = rank + N_EDGES;                     // NB_SCAN
    int* blockOffs = blockSums + NB_SCAN;                // NB_SCAN

    // transposed bf16 weight blocks (hi at +0, lo at +size)
    u16* W1aT = wT;                  // 16384 hi + 16384 lo
    u16* W1bT = wT + 32768;
    u16* W2aT = wT + 65536;
    u16* W2bT = wT + 98304;
    u16* Wf1T = wT + 131072;
    u16* Wf2T = wT + 163840;         // 8192 hi + 8192 lo

    const int mlpGrid = (N_NODES + 63) / 64;
    const int eGrid   = (N_EDGES + 255) / 256;
    const int nGrid   = (N_NODES + 255) / 256;
    const int fcGrid  = N_EDGES / 64;   // 9375, exact
    const int wpGrid  = (90112 + 255) / 256;

    // ---- build sorted CSR + bf16 weights (same work every call) ----
    hipMemsetAsync(counts, 0, (size_t)N_NODES * sizeof(int), stream);
    hist_k   <<<eGrid,   256, 0, stream>>>(dst, counts, rank);
    wprep_k  <<<wpGrid,  256, 0, stream>>>(W1a, W1b, W2a, W2b, Wf1, Wf2, wT);
    scan_a_k <<<NB_SCAN, 256, 0, stream>>>(counts, row_ptr, blockSums);
    scan_b_k <<<1,        64, 0, stream>>>(blockSums, blockOffs);
    scan_c_k <<<nGrid,   256, 0, stream>>>(row_ptr, blockOffs);
    scatter_k<<<eGrid,   256, 0, stream>>>(src, dst, row_ptr, rank, perm, src_s, dst_srt);

    // ---- conv1 (fully fused edge-linear + gather + relu + segment-sum) ----
    hipMemsetAsync(agg, 0, (size_t)N_NODES * 128 * sizeof(float), stream);
    fused_conv_k<<<fcGrid, 256, 0, stream>>>(x, ef, perm, src_s, dst_srt, row_ptr,
                                             We1, be1, agg);
    mlp2_mfma_k<8, false, true, true><<<mlpGrid, 256, 0, stream>>>(
        x, agg, W1aT, W1aT + 16384, b1a, W1bT, W1bT + 16384, b1b, h);

    // ---- conv2 ----
    hipMemsetAsync(agg, 0, (size_t)N_NODES * 128 * sizeof(float), stream);
    fused_conv_k<<<fcGrid, 256, 0, stream>>>(h, ef, perm, src_s, dst_srt, row_ptr,
                                             We2, be2, agg);
    mlp2_mfma_k<8, false, true, true><<<mlpGrid, 256, 0, stream>>>(
        h, agg, W2aT, W2aT + 16384, b2a, W2bT, W2bT + 16384, b2b, h);

    // ---- head ----
    mlp2_mfma_k<4, true, false, false><<<mlpGrid, 256, 0, stream>>>(
        h, nullptr, Wf1T, Wf1T + 16384, bf1, Wf2T, Wf2T + 8192, bf2, out);
}

// Round 4
// 550.152 us; speedup vs baseline: 1.2798x; 1.0430x over previous
//
#include <hip/hip_runtime.h>
#include <hip/hip_fp16.h>
#include <math.h>

#define N_NODES 100000
#define N_EDGES 600000
#define NB_SCAN ((N_NODES + 1023) / 1024)   // 98 scan blocks of 1024

typedef unsigned short u16;
typedef __bf16 bf16x8 __attribute__((ext_vector_type(8)));
typedef float  f32x4  __attribute__((ext_vector_type(4)));

__device__ __forceinline__ u16 f2bf(float f) {
    union { float f; unsigned u; } c; c.f = f;
    unsigned u = c.u + 0x7fffu + ((c.u >> 16) & 1u);   // RNE
    return (u16)(u >> 16);
}
__device__ __forceinline__ float bf2f(u16 h) {
    union { unsigned u; float f; } c; c.u = ((unsigned)h) << 16;
    return c.f;
}
// fast tanh: tanh(x) = 1 - 2/(exp(2x)+1); saturates correctly at +-inf.
__device__ __forceinline__ float fast_tanh(float x) {
    float e = __expf(2.0f * x);                 // v_exp_f32 path
    return 1.0f - 2.0f * __builtin_amdgcn_rcpf(e + 1.0f);
}

// ===========================================================================
// CSR build: counting sort of edges by dst (once per launch).
// ===========================================================================
__global__ void hist_k(const int* __restrict__ dst, int* __restrict__ counts,
                       int* __restrict__ rank)
{
    int e = blockIdx.x * 256 + threadIdx.x;
    if (e < N_EDGES) rank[e] = atomicAdd(&counts[dst[e]], 1);
}

__global__ void scan_a_k(const int* __restrict__ counts, int* __restrict__ row_ptr,
                         int* __restrict__ blockSums)
{
    __shared__ int s[256];
    const int t = threadIdx.x;
    const int base = blockIdx.x * 1024 + t * 4;
    int c[4];
#pragma unroll
    for (int j = 0; j < 4; ++j) c[j] = (base + j < N_NODES) ? counts[base + j] : 0;
    const int tot = c[0] + c[1] + c[2] + c[3];
    s[t] = tot;
    __syncthreads();
    for (int off = 1; off < 256; off <<= 1) {
        int v = (t >= off) ? s[t - off] : 0;
        __syncthreads();
        s[t] += v;
        __syncthreads();
    }
    int run = s[t] - tot;
#pragma unroll
    for (int j = 0; j < 4; ++j) {
        if (base + j < N_NODES) row_ptr[base + j] = run;
        run += c[j];
    }
    if (t == 255) blockSums[blockIdx.x] = s[255];
}

__global__ void scan_b_k(const int* __restrict__ blockSums, int* __restrict__ blockOffs)
{
    if (threadIdx.x == 0) {
        int run = 0;
        for (int b = 0; b < NB_SCAN; ++b) { blockOffs[b] = run; run += blockSums[b]; }
    }
}

__global__ void scan_c_k(int* __restrict__ row_ptr, const int* __restrict__ blockOffs)
{
    int i = blockIdx.x * 256 + threadIdx.x;
    if (i < N_NODES) row_ptr[i] += blockOffs[i >> 10];
    if (i == 0) row_ptr[N_NODES] = N_EDGES;
}

__global__ void scatter_k(const int* __restrict__ src, const int* __restrict__ dst,
                          const int* __restrict__ row_ptr, const int* __restrict__ rank,
                          int* __restrict__ perm, int* __restrict__ src_sorted,
                          int* __restrict__ dst_sorted)
{
    int e = blockIdx.x * 256 + threadIdx.x;
    if (e < N_EDGES) {
        int pos = row_ptr[dst[e]] + rank[e];
        perm[pos] = e;
        src_sorted[pos] = src[e];
        dst_sorted[pos] = dst[e];
    }
}

// ===========================================================================
// Weight prep (once per launch):
//  - node MLP weights: fp32 W[k][n] -> transposed bf16 hi/lo WT[n][128-k]
//  - edge-linear weights: fp32 We[32][128] -> transposed bf16 hi/lo WeT[n][32]
// ===========================================================================
__global__ void wprep_k(const float* __restrict__ W1a, const float* __restrict__ W1b,
                        const float* __restrict__ W2a, const float* __restrict__ W2b,
                        const float* __restrict__ Wf1, const float* __restrict__ Wf2,
                        const float* __restrict__ We1, const float* __restrict__ We2,
                        u16* __restrict__ wT)
{
    int idx = blockIdx.x * 256 + threadIdx.x;
    if (idx >= 98304) return;
    if (idx >= 90112) {                    // edge-linear WeT blocks
        int l = idx - 90112;               // 0..8191
        const int m = l >> 12;             // 0: We1, 1: We2
        l &= 4095;
        const float* src = m ? We2 : We1;
        const int k = l >> 7, n = l & 127; // We is [32][128]
        const float w = src[k * 128 + n];
        const u16 hi = f2bf(w);
        const u16 lo = f2bf(w - bf2f(hi));
        const int base = 180224 + m * 8192;
        wT[base + n * 32 + k]        = hi;
        wT[base + 4096 + n * 32 + k] = lo;
        return;
    }
    int m, local;
    if      (idx < 16384) { m = 0; local = idx; }
    else if (idx < 32768) { m = 1; local = idx - 16384; }
    else if (idx < 49152) { m = 2; local = idx - 32768; }
    else if (idx < 65536) { m = 3; local = idx - 49152; }
    else if (idx < 81920) { m = 4; local = idx - 65536; }
    else                  { m = 5; local = idx - 81920; }
    const int N = (m == 5) ? 64 : 128;
    const float* src = (m == 0) ? W1a : (m == 1) ? W1b : (m == 2) ? W2a
                     : (m == 3) ? W2b : (m == 4) ? Wf1 : Wf2;
    const int k = local / N, n = local % N;
    const float w = src[k * N + n];
    const u16 hi = f2bf(w);
    const u16 lo = f2bf(w - bf2f(hi));
    const int base = m * 32768;
    const int sz   = (m == 5) ? 8192 : 16384;
    wT[base + n * 128 + k]      = hi;
    wT[base + sz + n * 128 + k] = lo;
}

// ===========================================================================
// FUSED conv kernel (round 10): MFMA edge-linear + x-gather + relu + CSR
// segment-sum, one block per 64 sorted edges.
//   Phase 1: stage ef tile as bf16 hi/lo in LDS ([64][40] per component,
//     10 KB); each wave owns 2 output col-tiles, B-frags (WeT bf16 hi/lo,
//     16 VGPR) straight from L2; 24 MFMA/wave (3-term hi/lo ~ fp32) replace
//     1024 scalar FMA/thread. x[src] gathered per-lane (32 dwords) before
//     the MFMA block; add + relu in regs.
//   Phase 2 (proven): msg fp32 in LDS (overlays ef tiles); edges dst-sorted
//     -> per-node segment sums; interior nodes plain store, boundary nodes
//     atomicAdd (agg pre-zeroed).
// A-layout: A[m=lane&15][k=quad*8+j]; C/D: col=lane&15, row=quad*4+reg.
// ===========================================================================
__global__ __launch_bounds__(256, 4) void fused_conv_k(
    const float* __restrict__ x, const float* __restrict__ ef,
    const int* __restrict__ perm, const int* __restrict__ src_s,
    const int* __restrict__ dst_s, const int* __restrict__ row_ptr,
    const u16* __restrict__ WeT_hi, const u16* __restrict__ WeT_lo,
    const float* __restrict__ be, float* __restrict__ agg)
{
    __shared__ __align__(16) char smem[33792];      // union: ef hi/lo | msg
    u16 (*efHi)[40]   = (u16 (*)[40])smem;                   // 5120 B
    u16 (*efLo)[40]   = (u16 (*)[40])(smem + 5120);          // 5120 B
    float (*msg)[132] = (float (*)[132])smem;                // 33792 B overlay
    __shared__ int sSrc[64];
    __shared__ int sDst[64];

    const int t  = threadIdx.x;
    const int i0 = blockIdx.x * 64;

    // ---- stage: ef rows -> bf16 hi/lo tile; edge ids ----
    if (t < 64) { sSrc[t] = src_s[i0 + t]; sDst[t] = dst_s[i0 + t]; }
    {
        const int row = t >> 2;
        const int q   = t & 3;                      // k-range q*8 .. q*8+7
        const int e   = perm[i0 + row];
        const float* p = ef + (size_t)e * 32 + q * 8;
        const float4 v0 = *(const float4*)(p);
        const float4 v1 = *(const float4*)(p + 4);
        const float vv[8] = {v0.x, v0.y, v0.z, v0.w, v1.x, v1.y, v1.z, v1.w};
        unsigned hp[4], lp[4];
#pragma unroll
        for (int i = 0; i < 4; ++i) {
            const u16 h0 = f2bf(vv[2 * i]),     h1 = f2bf(vv[2 * i + 1]);
            const u16 l0 = f2bf(vv[2 * i]     - bf2f(h0));
            const u16 l1 = f2bf(vv[2 * i + 1] - bf2f(h1));
            hp[i] = (unsigned)h0 | ((unsigned)h1 << 16);
            lp[i] = (unsigned)l0 | ((unsigned)l1 << 16);
        }
        *(uint4*)&efHi[row][q * 8] = make_uint4(hp[0], hp[1], hp[2], hp[3]);
        *(uint4*)&efLo[row][q * 8] = make_uint4(lp[0], lp[1], lp[2], lp[3]);
    }
    __syncthreads();

    const int lane = t & 63, wave = t >> 6;
    const int quad = lane >> 4, col = lane & 15;

    // ---- B fragments (WeT, L2-hot) for this wave's 2 col-tiles ----
    bf16x8 bHi[2], bLo[2];
#pragma unroll
    for (int j = 0; j < 2; ++j) {
        const int nt = wave * 2 + j;
        const size_t off = (size_t)(nt * 16 + col) * 32 + quad * 8;
        bHi[j] = *(const bf16x8*)(WeT_hi + off);
        bLo[j] = *(const bf16x8*)(WeT_lo + off);
    }

    // ---- x gather (32 independent dwords; latency hides under MFMA) ----
    float xv[2][4][4];
#pragma unroll
    for (int m = 0; m < 4; ++m)
#pragma unroll
        for (int r = 0; r < 4; ++r) {
            const int s = sSrc[m * 16 + quad * 4 + r];
            const float* xp = x + (size_t)s * 128 + wave * 32 + col;
            xv[0][m][r] = xp[0];
            xv[1][m][r] = xp[16];
        }

    // ---- MFMA: e = ef @ We + be (3-term hi/lo) ----
    f32x4 acc[2][4];
#pragma unroll
    for (int j = 0; j < 2; ++j) {
        const float bv = be[wave * 32 + j * 16 + col];
#pragma unroll
        for (int m = 0; m < 4; ++m) acc[j][m] = (f32x4){bv, bv, bv, bv};
    }
#pragma unroll
    for (int m = 0; m < 4; ++m) {
        const bf16x8 aHi = *(const bf16x8*)&efHi[m * 16 + col][quad * 8];
        const bf16x8 aLo = *(const bf16x8*)&efLo[m * 16 + col][quad * 8];
#pragma unroll
        for (int j = 0; j < 2; ++j) {
            acc[j][m] = __builtin_amdgcn_mfma_f32_16x16x32_bf16(aHi, bHi[j], acc[j][m], 0, 0, 0);
            acc[j][m] = __builtin_amdgcn_mfma_f32_16x16x32_bf16(aHi, bLo[j], acc[j][m], 0, 0, 0);
            acc[j][m] = __builtin_amdgcn_mfma_f32_16x16x32_bf16(aLo, bHi[j], acc[j][m], 0, 0, 0);
        }
    }

    // ---- msg = relu(x + e) in regs ----
#pragma unroll
    for (int j = 0; j < 2; ++j)
#pragma unroll
        for (int m = 0; m < 4; ++m)
#pragma unroll
            for (int r = 0; r < 4; ++r)
                acc[j][m][r] = fmaxf(acc[j][m][r] + xv[j][m][r], 0.f);

    __syncthreads();            // all ef-tile reads done -> overlay as msg
#pragma unroll
    for (int j = 0; j < 2; ++j)
#pragma unroll
        for (int m = 0; m < 4; ++m)
#pragma unroll
            for (int r = 0; r < 4; ++r)
                msg[m * 16 + quad * 4 + r][wave * 32 + j * 16 + col] = acc[j][m][r];
    __syncthreads();

    // ---- phase 2: per-node segment sum + store/atomic ----
    const int c2 = lane * 2;
    const int nF = sDst[0], nL = sDst[63];
    for (int n = nF + wave; n <= nL; n += 4) {
        const int rs = row_ptr[n];
        const int re = row_ptr[n + 1];
        const int lo = rs > i0 ? rs : i0;
        const int hi = re < i0 + 64 ? re : i0 + 64;
        float a0 = 0.f, a1 = 0.f;
        for (int i = lo; i < hi; ++i) {
            const float2 v = *(const float2*)(&msg[i - i0][c2]);
            a0 += v.x; a1 += v.y;
        }
        float* dp = agg + (size_t)n * 128 + c2;
        const bool interior = (rs >= i0) && (re <= i0 + 64);
        if (interior) {
            *(float2*)dp = make_float2(a0, a1);
        } else if (hi > lo) {
            atomicAdd(dp,     a0);
            atomicAdd(dp + 1, a1);
        }
    }
}

// ===========================================================================
// Fused 2-layer node MLP via bf16 hi/lo split MFMA (16x16x32) — unchanged
// from round 7 (column-split wave mapping, B-frags reused across 4 row
// subtiles, acc held across barrier, fast_tanh).
// ===========================================================================
template <int NT2, bool TANH1, bool TANHF, bool ADDAGG>
__global__ __launch_bounds__(256, 4) void mlp2_mfma_k(
    const float* __restrict__ xin, const float* __restrict__ agg,
    const u16* __restrict__ WaT_hi, const u16* __restrict__ WaT_lo,
    const float* __restrict__ ba,
    const u16* __restrict__ WbT_hi, const u16* __restrict__ WbT_lo,
    const float* __restrict__ bb,
    float* __restrict__ out)
{
    __shared__ u16 sHi[64][136];
    __shared__ u16 sLo[64][136];
    const int tid = threadIdx.x;
    const int n0  = blockIdx.x * 64;

    // ---- stage tile: fp32 (xin + agg) -> bf16 hi/lo in LDS ----
    {
        const int mrow = tid >> 5, kq = tid & 31;
#pragma unroll
        for (int g = 0; g < 8; ++g) {
            const int row  = g * 8 + mrow;
            const int node = n0 + row;
            float4 v = make_float4(0.f, 0.f, 0.f, 0.f);
            if (node < N_NODES) {
                v = *(const float4*)(xin + (size_t)node * 128 + kq * 4);
                if (ADDAGG) {
                    float4 a4 = *(const float4*)(agg + (size_t)node * 128 + kq * 4);
                    v.x += a4.x; v.y += a4.y; v.z += a4.z; v.w += a4.w;
                }
            }
            const u16 h0 = f2bf(v.x), h1 = f2bf(v.y), h2 = f2bf(v.z), h3 = f2bf(v.w);
            const u16 l0 = f2bf(v.x - bf2f(h0)), l1 = f2bf(v.y - bf2f(h1));
            const u16 l2 = f2bf(v.z - bf2f(h2)), l3 = f2bf(v.w - bf2f(h3));
            *(uint2*)&sHi[row][kq * 4] =
                make_uint2((unsigned)h0 | ((unsigned)h1 << 16), (unsigned)h2 | ((unsigned)h3 << 16));
            *(uint2*)&sLo[row][kq * 4] =
                make_uint2((unsigned)l0 | ((unsigned)l1 << 16), (unsigned)l2 | ((unsigned)l3 << 16));
        }
    }
    __syncthreads();

    const int lane = tid & 63, wave = tid >> 6;
    const int quad = lane >> 4, col = lane & 15;

    // ---- layer A: wave w owns col-tiles nt = 2w+j (j=0,1), all 64 rows ----
    f32x4 accA[2][4];
#pragma unroll
    for (int j = 0; j < 2; ++j) {
        const int nt = wave * 2 + j;
        const float bv = ba[nt * 16 + col];
#pragma unroll
        for (int m = 0; m < 4; ++m) accA[j][m] = (f32x4){bv, bv, bv, bv};

        bf16x8 bHi[4], bLo[4];
#pragma unroll
        for (int k0 = 0; k0 < 4; ++k0) {
            const size_t off = (size_t)(nt * 16 + col) * 128 + k0 * 32 + quad * 8;
            bHi[k0] = *(const bf16x8*)(WaT_hi + off);
            bLo[k0] = *(const bf16x8*)(WaT_lo + off);
        }
#pragma unroll 2
        for (int m = 0; m < 4; ++m) {
#pragma unroll
            for (int k0 = 0; k0 < 4; ++k0) {
                const bf16x8 aHi = *(const bf16x8*)&sHi[m * 16 + col][k0 * 32 + quad * 8];
                const bf16x8 aLo = *(const bf16x8*)&sLo[m * 16 + col][k0 * 32 + quad * 8];
                accA[j][m] = __builtin_amdgcn_mfma_f32_16x16x32_bf16(aHi, bHi[k0], accA[j][m], 0, 0, 0);
                accA[j][m] = __builtin_amdgcn_mfma_f32_16x16x32_bf16(aHi, bLo[k0], accA[j][m], 0, 0, 0);
                accA[j][m] = __builtin_amdgcn_mfma_f32_16x16x32_bf16(aLo, bHi[k0], accA[j][m], 0, 0, 0);
            }
        }
    }
    __syncthreads();   // all waves done READING the input tile

    // ---- act1 + hi/lo re-split of t into the same LDS buffer ----
#pragma unroll
    for (int j = 0; j < 2; ++j) {
        const int ct = (wave * 2 + j) * 16 + col;
#pragma unroll
        for (int m = 0; m < 4; ++m) {
#pragma unroll
            for (int r = 0; r < 4; ++r) {
                float v = TANH1 ? fast_tanh(accA[j][m][r]) : fmaxf(accA[j][m][r], 0.f);
                const u16 hv = f2bf(v);
                const u16 lv = f2bf(v - bf2f(hv));
                const int row = m * 16 + quad * 4 + r;
                sHi[row][ct] = hv;
                sLo[row][ct] = lv;
            }
        }
    }
    __syncthreads();   // t tile fully written

    // ---- layer B: same mapping; head (NT2=4) = 1 col-tile per wave ----
    constexpr int JB   = NT2 / 4;
    constexpr int NOUT = NT2 * 16;
#pragma unroll
    for (int j = 0; j < JB; ++j) {
        const int nt = wave * JB + j;
        const float bv = bb[nt * 16 + col];
        f32x4 accB[4];
#pragma unroll
        for (int m = 0; m < 4; ++m) accB[m] = (f32x4){bv, bv, bv, bv};

        bf16x8 bHi[4], bLo[4];
#pragma unroll
        for (int k0 = 0; k0 < 4; ++k0) {
            const size_t off = (size_t)(nt * 16 + col) * 128 + k0 * 32 + quad * 8;
            bHi[k0] = *(const bf16x8*)(WbT_hi + off);
            bLo[k0] = *(const bf16x8*)(WbT_lo + off);
        }
#pragma unroll 2
        for (int m = 0; m < 4; ++m) {
#pragma unroll
            for (int k0 = 0; k0 < 4; ++k0) {
                const bf16x8 tHi = *(const bf16x8*)&sHi[m * 16 + col][k0 * 32 + quad * 8];
                const bf16x8 tLo = *(const bf16x8*)&sLo[m * 16 + col][k0 * 32 + quad * 8];
                accB[m] = __builtin_amdgcn_mfma_f32_16x16x32_bf16(tHi, bHi[k0], accB[m], 0, 0, 0);
                accB[m] = __builtin_amdgcn_mfma_f32_16x16x32_bf16(tHi, bLo[k0], accB[m], 0, 0, 0);
                accB[m] = __builtin_amdgcn_mfma_f32_16x16x32_bf16(tLo, bHi[k0], accB[m], 0, 0, 0);
            }
        }
#pragma unroll
        for (int m = 0; m < 4; ++m) {
#pragma unroll
            for (int r = 0; r < 4; ++r) {
                const int node = n0 + m * 16 + quad * 4 + r;
                if (node < N_NODES) {
                    float v = accB[m][r];
                    if (TANHF) v = fast_tanh(v);
                    out[(size_t)node * NOUT + nt * 16 + col] = v;
                }
            }
        }
    }
}

// ---------------------------------------------------------------------------
extern "C" void kernel_launch(void* const* d_in, const int* in_sizes, int n_in,
                              void* d_out, int out_size, void* d_ws, size_t ws_size,
                              hipStream_t stream)
{
    const float* x   = (const float*)d_in[0];
    const int*   ei  = (const int*)  d_in[1];
    const float* ef  = (const float*)d_in[2];
    const float* We1 = (const float*)d_in[3];
    const float* be1 = (const float*)d_in[4];
    const float* W1a = (const float*)d_in[5];
    const float* b1a = (const float*)d_in[6];
    const float* W1b = (const float*)d_in[7];
    const float* b1b = (const float*)d_in[8];
    const float* We2 = (const float*)d_in[9];
    const float* be2 = (const float*)d_in[10];
    const float* W2a = (const float*)d_in[11];
    const float* b2a = (const float*)d_in[12];
    const float* W2b = (const float*)d_in[13];
    const float* b2b = (const float*)d_in[14];
    const float* Wf1 = (const float*)d_in[15];
    const float* bf1 = (const float*)d_in[16];
    const float* Wf2 = (const float*)d_in[17];
    const float* bf2 = (const float*)d_in[18];
    float* out = (float*)d_out;

    const int* src = ei;             // edge_index[0]
    const int* dst = ei + N_EDGES;   // edge_index[1]

    // ---- workspace layout ----
    float*  agg     = (float*)d_ws;                      // N*128 f
    float*  h       = agg + (size_t)N_NODES * 128;       // N*128 f
    int*    row_ptr = (int*)(h + (size_t)N_NODES * 128); // N+8 (padded)
    int*    perm    = row_ptr + (N_NODES + 8);           // E
    int*    src_s   = perm + N_EDGES;                    // E
    int*    dst_srt = src_s + N_EDGES;                   // E
    u16*    wT      = (u16*)(dst_srt + N_EDGES);         // 196608 u16 bf16 weights
    // sort temporaries overlaid on agg (dead before agg memset):
    int* counts    = (int*)agg;                          // N
    int* rank      = counts + N_NODES;                   // E
    int* blockSums = rank + N_EDGES;                     // NB_SCAN
    int* blockOffs = blockSums + NB_SCAN;                // NB_SCAN

    // transposed bf16 weight blocks (hi at +0, lo at +size)
    u16* W1aT = wT;                  // 16384 hi + 16384 lo
    u16* W1bT = wT + 32768;
    u16* W2aT = wT + 65536;
    u16* W2bT = wT + 98304;
    u16* Wf1T = wT + 131072;
    u16* Wf2T = wT + 163840;         // 8192 hi + 8192 lo
    u16* We1T = wT + 180224;         // 4096 hi + 4096 lo
    u16* We2T = wT + 188416;         // 4096 hi + 4096 lo

    const int mlpGrid = (N_NODES + 63) / 64;
    const int eGrid   = (N_EDGES + 255) / 256;
    const int nGrid   = (N_NODES + 255) / 256;
    const int fcGrid  = N_EDGES / 64;   // 9375, exact
    const int wpGrid  = (98304 + 255) / 256;

    // ---- build sorted CSR + bf16 weights (same work every call) ----
    hipMemsetAsync(counts, 0, (size_t)N_NODES * sizeof(int), stream);
    hist_k   <<<eGrid,   256, 0, stream>>>(dst, counts, rank);
    wprep_k  <<<wpGrid,  256, 0, stream>>>(W1a, W1b, W2a, W2b, Wf1, Wf2, We1, We2, wT);
    scan_a_k <<<NB_SCAN, 256, 0, stream>>>(counts, row_ptr, blockSums);
    scan_b_k <<<1,        64, 0, stream>>>(blockSums, blockOffs);
    scan_c_k <<<nGrid,   256, 0, stream>>>(row_ptr, blockOffs);
    scatter_k<<<eGrid,   256, 0, stream>>>(src, dst, row_ptr, rank, perm, src_s, dst_srt);

    // ---- conv1 (fully fused MFMA edge-linear + gather + relu + segsum) ----
    hipMemsetAsync(agg, 0, (size_t)N_NODES * 128 * sizeof(float), stream);
    fused_conv_k<<<fcGrid, 256, 0, stream>>>(x, ef, perm, src_s, dst_srt, row_ptr,
                                             We1T, We1T + 4096, be1, agg);
    mlp2_mfma_k<8, false, true, true><<<mlpGrid, 256, 0, stream>>>(
        x, agg, W1aT, W1aT + 16384, b1a, W1bT, W1bT + 16384, b1b, h);

    // ---- conv2 ----
    hipMemsetAsync(agg, 0, (size_t)N_NODES * 128 * sizeof(float), stream);
    fused_conv_k<<<fcGrid, 256, 0, stream>>>(h, ef, perm, src_s, dst_srt, row_ptr,
                                             We2T, We2T + 4096, be2, agg);
    mlp2_mfma_k<8, false, true, true><<<mlpGrid, 256, 0, stream>>>(
        h, agg, W2aT, W2aT + 16384, b2a, W2bT, W2bT + 16384, b2b, h);

    // ---- head ----
    mlp2_mfma_k<4, true, false, false><<<mlpGrid, 256, 0, stream>>>(
        h, nullptr, Wf1T, Wf1T + 16384, bf1, Wf2T, Wf2T + 8192, bf2, out);
}